// Round 1
// baseline (625.583 us; speedup 1.0000x reference)
//
#include <hip/hip_runtime.h>
#include <hip/hip_cooperative_groups.h>
#include <cstdint>

namespace cg = cooperative_groups;

// Problem constants (fixed by the reference file).
#define Bn 64
#define Cn 256
#define Hn 56
#define Wn 56
#define HM 52            // H - (BS-1)
#define WM 52
#define BS 5
#define NPLANES (Bn * Cn)          // 16384
#define PLANE (Hn * Wn)            // 3136
#define ROW_I4 13                  // 52 ints = 13 int4 per mask row
#define PLANE_I4 (HM * ROW_I4)     // 676 int4 per mask plane
#define COUNTM ((long long)NPLANES * PLANE)  // 51380224

// Fused-kernel geometry.
#define GRID 1024
#define BLOCK 256
#define THREADS (GRID * BLOCK)            // 262144
#define PLANES_PER_BLOCK (NPLANES / GRID) // 16
#define PPG 4                             // planes staged in LDS per group
#define GROUPS (PLANES_PER_BLOCK / PPG)   // 4
#define N4 (COUNTM / 4)                   // 12,845,056 float4
#define APPLY_ITERS (N4 / THREADS)        // 49, exact

// ---------------------------------------------------------------------------
// Single cooperative kernel, three phases:
//   P1: dilate 16 planes/block (4 at a time so the vertical-OR tail runs with
//       224 active threads instead of 56), write packed uint64 rows, fold the
//       popcount into the tail and reduce per block into partial[bid]
//       (NO global atomics — R2 showed 16384 same-address atomicAdds cost
//       ~209 µs; here partials are plain stores).
//   grid.sync (+ __threadfence for cross-XCD L2 visibility of dil/partial)
//   P2: every block sums the 1024 partials (1 KB from L2) -> scale.
//   P3: float4 streaming apply, grid-stride, exactly 49 iterations.
// This replaces memset + 3 kernels with ONE dispatch and deletes the old
// count_kernel's 7.3 MB dil re-read.
// ---------------------------------------------------------------------------
__global__ __launch_bounds__(BLOCK, 4) void fused_kernel(
    const int4* __restrict__ mask4,
    const float4* __restrict__ x4,
    uint64_t* __restrict__ dil,
    int* __restrict__ partial,
    float4* __restrict__ out4)
{
    __shared__ unsigned long long hrow[PPG * HM];   // 4 planes x 52 rows
    __shared__ int red[4];
    __shared__ float s_scale;

    const int tid = threadIdx.x;
    const int bid = blockIdx.x;

    // ---------------- Phase 1: dilate + count ----------------
    int pc = 0;
    for (int g = 0; g < GROUPS; ++g) {
        if (tid < PPG * HM) hrow[tid] = 0ull;       // 208 entries
        __syncthreads();

        const int plane0 = bid * PLANES_PER_BLOCK + g * PPG;
        const int4* mbase = mask4 + (size_t)plane0 * PLANE_I4;

        // 4 planes = 2704 int4 over 256 threads -> 11 coalesced iterations.
        #pragma unroll
        for (int k = 0; k < 11; ++k) {
            const int i = tid + k * 256;
            if (i < PPG * PLANE_I4) {
                const int4 m = mbase[i];
                const unsigned nib = (m.x != 0 ? 1u : 0u) | (m.y != 0 ? 2u : 0u) |
                                     (m.z != 0 ? 4u : 0u) | (m.w != 0 ? 8u : 0u);
                if (nib) {                          // ~92% of lanes skip
                    const int p   = i / PLANE_I4;
                    const int rem = i - p * PLANE_I4;
                    const int row = rem / ROW_I4;
                    const int c4  = (rem - row * ROW_I4) * 4;
                    atomicOr(&hrow[p * HM + row], (unsigned long long)nib << c4);
                }
            }
        }
        __syncthreads();

        if (tid < PPG * Hn) {                       // 224 active threads
            const int p = tid / Hn;
            const int r = tid - p * Hn;
            int lo = r - (BS - 1); if (lo < 0) lo = 0;
            int hi = r;            if (hi > HM - 1) hi = HM - 1;
            unsigned long long acc = 0ull;
            for (int q = lo; q <= hi; ++q) acc |= hrow[p * HM + q];
            // horizontal dilation commutes with the vertical OR; bits 0..55
            acc = acc | (acc << 1) | (acc << 2) | (acc << 3) | (acc << 4);
            dil[(size_t)(plane0 + p) * Hn + r] = acc;
            pc += __popcll(acc);
        }
        __syncthreads();                            // protect hrow re-zero
    }

    // Block-reduce dropped-cell count; one plain store per block.
    #pragma unroll
    for (int off = 32; off > 0; off >>= 1) pc += __shfl_down(pc, off, 64);
    if ((tid & 63) == 0) red[tid >> 6] = pc;
    __syncthreads();
    if (tid == 0) partial[bid] = red[0] + red[1] + red[2] + red[3];

    // Make dil/partial visible across XCDs, then grid barrier.
    __threadfence();
    cg::this_grid().sync();

    // ---------------- Phase 2: global count -> scale ----------------
    int t = 0;
    #pragma unroll
    for (int k = 0; k < GRID / BLOCK; ++k) t += partial[tid + k * BLOCK];
    #pragma unroll
    for (int off = 32; off > 0; off >>= 1) t += __shfl_down(t, off, 64);
    if ((tid & 63) == 0) red[tid >> 6] = t;
    __syncthreads();
    if (tid == 0) {
        const long long ones = COUNTM - (long long)(red[0] + red[1] + red[2] + red[3]);
        s_scale = (float)COUNTM / (float)ones;      // f32 divide, matches ref
    }
    __syncthreads();
    const float scale = s_scale;

    // ---------------- Phase 3: apply ----------------
    const int gtid = bid * BLOCK + tid;
    #pragma unroll 1
    for (int k = 0; k < APPLY_ITERS; ++k) {
        const int i = gtid + k * THREADS;           // coalesced across lanes
        const int plane = i / (PLANE / 4);          // 784 float4 per plane
        const int r4    = i - plane * (PLANE / 4);
        const int h     = r4 / (Wn / 4);            // 14 float4 per row
        const int w0    = (r4 - h * (Wn / 4)) * 4;  // in {0,4,...,52}

        const uint64_t row = dil[plane * Hn + h];
        const unsigned bits = (unsigned)(row >> w0) & 0xFu;

        const float4 v = x4[i];
        float4 o;
        o.x = (bits & 1u) ? 0.0f : v.x * scale;
        o.y = (bits & 2u) ? 0.0f : v.y * scale;
        o.z = (bits & 4u) ? 0.0f : v.z * scale;
        o.w = (bits & 8u) ? 0.0f : v.w * scale;
        out4[i] = o;
    }
}

extern "C" void kernel_launch(void* const* d_in, const int* in_sizes, int n_in,
                              void* d_out, int out_size, void* d_ws, size_t ws_size,
                              hipStream_t stream)
{
    const int4*   mask4 = (const int4*)d_in[1];
    const float4* x4    = (const float4*)d_in[0];
    // d_in[2] = block_size (scalar 5) — fixed by the reference, hardcoded.

    uint64_t* dil     = (uint64_t*)d_ws;                         // 7,340,032 B
    int*      partial = (int*)((char*)d_ws + (size_t)NPLANES * Hn * 8); // +4 KB
    float4*   out4    = (float4*)d_out;

    // partial[] is fully written by every block before use — no memset needed.
    void* args[] = { (void*)&mask4, (void*)&x4, (void*)&dil,
                     (void*)&partial, (void*)&out4 };
    hipLaunchCooperativeKernel((void*)fused_kernel, dim3(GRID), dim3(BLOCK),
                               args, 0, stream);
}

// Round 2
// 442.771 us; speedup vs baseline: 1.4129x; 1.4129x over previous
//
#include <hip/hip_runtime.h>
#include <cstdint>

// Problem constants (fixed by the reference file).
#define Bn 64
#define Cn 256
#define Hn 56
#define Wn 56
#define HM 52            // H - (BS-1)
#define WM 52
#define BS 5
#define NPLANES (Bn * Cn)          // 16384
#define PLANE (Hn * Wn)            // 3136
#define ROW_I4 13                  // 52 ints = 13 int4 per mask row
#define PLANE_I4 (HM * ROW_I4)     // 676 int4 per mask plane
#define COUNTM ((long long)NPLANES * PLANE)  // 51380224

// Apply geometry: 4 float4 per thread, exact cover.
#define N4 ((int)(COUNTM / 4))     // 12,845,056
#define APPLY_PER_THREAD 4
#define APPLY_THREADS (N4 / APPLY_PER_THREAD)      // 3,211,264
#define APPLY_BLOCKS (APPLY_THREADS / 256)         // 12,544

// ---------------------------------------------------------------------------
// Pass 1: one block per (b,c) plane (16384 blocks — max TLP; R1 showed that
// shrinking this grid makes the chain latency-bound). Load mask as int4,
// build per-row bitmasks via sparse LDS atomicOr, vertical OR window +
// horizontal shift-OR, write 56 packed uint64 rows, AND fold the popcount
// into the tail: rows 0..55 all live in wave 0, so a single wave-shuffle
// gives the block total -> one plain store to partial[bid]. No global
// atomics (R2: 16384 same-address atomicAdds serialized ~209 µs).
// ---------------------------------------------------------------------------
__global__ __launch_bounds__(256) void dilate_kernel(
    const int4* __restrict__ mask4,
    uint64_t* __restrict__ dil,
    int* __restrict__ partial)
{
    __shared__ unsigned long long hrow[HM];

    const int plane = blockIdx.x;
    const int tid   = threadIdx.x;

    if (tid < HM) hrow[tid] = 0ull;
    __syncthreads();

    const int4* mbase = mask4 + (size_t)plane * PLANE_I4;

    // 676 = 2*256 + 164 : threads issue 2-3 independent 16B loads.
    #pragma unroll
    for (int k = 0; k < 3; ++k) {
        const int i = tid + k * 256;
        if (i < PLANE_I4) {
            const int4 m = mbase[i];
            const unsigned nib = (m.x != 0 ? 1u : 0u) | (m.y != 0 ? 2u : 0u) |
                                 (m.z != 0 ? 4u : 0u) | (m.w != 0 ? 8u : 0u);
            if (nib) {                      // ~92% skipped at gamma=0.02
                const int row = i / ROW_I4;
                const int c4  = (i - row * ROW_I4) * 4;
                atomicOr(&hrow[row], (unsigned long long)nib << c4);
            }
        }
    }
    __syncthreads();

    int pc = 0;
    if (tid < Hn) {
        // vertical OR window over raw rows [tid-4, tid] clamped to [0,51]
        int lo = tid - (BS - 1); if (lo < 0) lo = 0;
        int hi = tid;            if (hi > HM - 1) hi = HM - 1;
        unsigned long long acc = 0ull;
        for (int r = lo; r <= hi; ++r) acc |= hrow[r];
        // horizontal dilation (commutes with vertical OR); bits land in 0..55
        acc = acc | (acc << 1) | (acc << 2) | (acc << 3) | (acc << 4);
        dil[(size_t)plane * Hn + tid] = acc;
        pc = __popcll(acc);
    }

    // tid 0..55 are all in wave 0 -> single-wave reduce, no cross-wave step.
    if (tid < 64) {
        #pragma unroll
        for (int off = 32; off > 0; off >>= 1)
            pc += __shfl_down(pc, off, 64);
        if (tid == 0) partial[plane] = pc;
    }
}

// ---------------------------------------------------------------------------
// Pass 1.5: single-block reduce of 16384 partials (64 KB from L2) -> the
// final f32 scale, computed exactly as before: (float)COUNTM / (float)ones.
// Launch-overhead-dominated (~4 µs) vs the old count_kernel's 7.3 MB pass.
// ---------------------------------------------------------------------------
__global__ __launch_bounds__(256) void reduce_kernel(
    const int* __restrict__ partial,
    float* __restrict__ scale_out)
{
    __shared__ int wsum[4];
    int t = 0;
    #pragma unroll
    for (int k = 0; k < NPLANES / 256; ++k)        // 64 coalesced iterations
        t += partial[threadIdx.x + k * 256];

    #pragma unroll
    for (int off = 32; off > 0; off >>= 1)
        t += __shfl_down(t, off, 64);
    if ((threadIdx.x & 63) == 0) wsum[threadIdx.x >> 6] = t;
    __syncthreads();
    if (threadIdx.x == 0) {
        const long long dropped = wsum[0] + wsum[1] + wsum[2] + wsum[3];
        const long long ones = COUNTM - dropped;
        *scale_out = (float)COUNTM / (float)ones;
    }
}

// ---------------------------------------------------------------------------
// Pass 2: float4 streaming apply. 4 float4 per thread, fully unrolled ->
// 4 independent {dil, x4} load chains per thread for MLP, 12544 blocks
// keeps the TLP that R1's fused version lost.
// ---------------------------------------------------------------------------
__global__ __launch_bounds__(256) void apply_kernel(
    const float4* __restrict__ x4,
    const uint64_t* __restrict__ dil,
    const float* __restrict__ scale_in,
    float4* __restrict__ out4)
{
    const float scale = *scale_in;                 // scalar, L2-broadcast
    const int gtid = blockIdx.x * 256 + threadIdx.x;

    #pragma unroll
    for (int k = 0; k < APPLY_PER_THREAD; ++k) {
        const int i = gtid + k * APPLY_THREADS;    // coalesced across lanes
        const int plane = i / (PLANE / 4);         // 784 float4 per plane
        const int r4    = i - plane * (PLANE / 4);
        const int h     = r4 / (Wn / 4);           // 14 float4 per row
        const int w0    = (r4 - h * (Wn / 4)) * 4; // in {0,4,...,52}

        const uint64_t row = dil[plane * Hn + h];
        const unsigned bits = (unsigned)(row >> w0) & 0xFu;

        const float4 v = x4[i];
        float4 o;
        o.x = (bits & 1u) ? 0.0f : v.x * scale;
        o.y = (bits & 2u) ? 0.0f : v.y * scale;
        o.z = (bits & 4u) ? 0.0f : v.z * scale;
        o.w = (bits & 8u) ? 0.0f : v.w * scale;
        out4[i] = o;
    }
}

extern "C" void kernel_launch(void* const* d_in, const int* in_sizes, int n_in,
                              void* d_out, int out_size, void* d_ws, size_t ws_size,
                              hipStream_t stream)
{
    const float4* x4    = (const float4*)d_in[0];
    const int4*   mask4 = (const int4*)d_in[1];
    // d_in[2] = block_size (scalar 5) — fixed by the reference, hardcoded.

    uint64_t* dil     = (uint64_t*)d_ws;                          // 7,340,032 B
    int*      partial = (int*)((char*)d_ws + (size_t)NPLANES * Hn * 8);
    float*    scale   = (float*)((char*)d_ws + (size_t)NPLANES * Hn * 8
                                             + (size_t)NPLANES * 4);

    // Every ws word used is written before it is read (dil, partial, scale),
    // so the 0xAA re-poison needs no memset — zero extra dispatches.
    dilate_kernel<<<NPLANES, 256, 0, stream>>>(mask4, dil, partial);
    reduce_kernel<<<1, 256, 0, stream>>>(partial, scale);
    apply_kernel<<<APPLY_BLOCKS, 256, 0, stream>>>(x4, dil, scale, (float4*)d_out);
}